// Round 6
// baseline (236.692 us; speedup 1.0000x reference)
//
#include <hip/hip_runtime.h>

#define BATCH 2
#define SEQ   4096
#define HID   256
#define NHEAD 8
#define DH    32
// defer-max threshold in log2 units (≈ 8 nats)
#define THR_L2 11.5f
// 1/sqrt(32) * log2(e)
#define QSCALE 0.25501639769925074f
// -(1/10) * log2(e)
#define BIASC (-0.14426950408889634f)

typedef __attribute__((ext_vector_type(8))) _Float16 half8;
typedef __attribute__((ext_vector_type(4))) _Float16 half4;
typedef __attribute__((ext_vector_type(2))) __fp16   fp16x2;
typedef __attribute__((ext_vector_type(4))) float    f32x4;

__device__ __forceinline__ float fast_exp2(float x) {
    return __builtin_amdgcn_exp2f(x);
}

// ---------------------------------------------------------------- convert
__global__ void cvt_f32_f16(const float* __restrict__ src,
                            _Float16* __restrict__ dst, int n) {
    int i = (blockIdx.x * blockDim.x + threadIdx.x) * 4;
    if (i >= n) return;
    f32x4 v = *reinterpret_cast<const f32x4*>(src + i);
    half4 h;
#pragma unroll
    for (int c = 0; c < 4; ++c) h[c] = (_Float16)v[c];
    *reinterpret_cast<half4*>(dst + i) = h;
}

__global__ void cvt_w4(const float* __restrict__ a, const float* __restrict__ b,
                       const float* __restrict__ c, const float* __restrict__ d,
                       _Float16* __restrict__ dst) {
    const float* srcs[4] = {a, b, c, d};
    const float* s = srcs[blockIdx.y];
    const int i = (blockIdx.x * blockDim.x + threadIdx.x) * 4;
    f32x4 v = *reinterpret_cast<const f32x4*>(s + i);
    half4 h;
#pragma unroll
    for (int k = 0; k < 4; ++k) h[k] = (_Float16)v[k];
    *reinterpret_cast<half4*>(dst + (size_t)blockIdx.y * HID * HID + i) = h;
}

// ---------------------------------------------------------------- QKV proj
__global__ __launch_bounds__(256) void qkv_proj(
    const _Float16* __restrict__ xh, const _Float16* __restrict__ Wh,
    const float* __restrict__ bq, const float* __restrict__ bk,
    const float* __restrict__ bv,
    _Float16* __restrict__ Qh, _Float16* __restrict__ Kh,
    _Float16* __restrict__ Vt)
{
    const int z   = blockIdx.z;
    const int m0  = blockIdx.x * 64;
    const int n0  = blockIdx.y * 64;
    const int tid = threadIdx.x;
    const int w   = tid >> 6, lane = tid & 63;
    const int lr  = lane & 15, lg = lane >> 4;
    const int wr  = (w >> 1) * 32, wc = (w & 1) * 32;

    const _Float16* Wp = Wh + (size_t)z * HID * HID;
    const float* bias = (z == 0) ? bq : (z == 1) ? bk : bv;

    f32x4 acc[2][2] = {};
    const int ar = m0 + wr + lr;
    const int br = n0 + wc + lr;
#pragma unroll
    for (int ks = 0; ks < 8; ++ks) {
        const int ko = ks * 32 + lg * 8;
        half8 a0 = *reinterpret_cast<const half8*>(xh + (size_t)ar * HID + ko);
        half8 a1 = *reinterpret_cast<const half8*>(xh + (size_t)(ar + 16) * HID + ko);
        half8 b0 = *reinterpret_cast<const half8*>(Wp + (size_t)br * HID + ko);
        half8 b1 = *reinterpret_cast<const half8*>(Wp + (size_t)(br + 16) * HID + ko);
        acc[0][0] = __builtin_amdgcn_mfma_f32_16x16x32_f16(a0, b0, acc[0][0], 0, 0, 0);
        acc[0][1] = __builtin_amdgcn_mfma_f32_16x16x32_f16(a0, b1, acc[0][1], 0, 0, 0);
        acc[1][0] = __builtin_amdgcn_mfma_f32_16x16x32_f16(a1, b0, acc[1][0], 0, 0, 0);
        acc[1][1] = __builtin_amdgcn_mfma_f32_16x16x32_f16(a1, b1, acc[1][1], 0, 0, 0);
    }
#pragma unroll
    for (int mf = 0; mf < 2; ++mf)
#pragma unroll
    for (int nf = 0; nf < 2; ++nf)
#pragma unroll
    for (int r = 0; r < 4; ++r) {
        const int m  = m0 + wr + mf * 16 + lg * 4 + r;
        const int o  = n0 + wc + nf * 16 + lr;
        const int bb = m >> 12, nn = m & (SEQ - 1);
        const int hh = o >> 5,  dd = o & (DH - 1);
        float v = acc[mf][nf][r] + bias[o];
        if (z == 0) {
            Qh[(((size_t)(bb * NHEAD + hh) * SEQ) + nn) * DH + dd] =
                (_Float16)(v * QSCALE);
        } else if (z == 1) {
            Kh[(((size_t)(bb * NHEAD + hh) * SEQ) + nn) * DH + dd] = (_Float16)v;
        } else {
            Vt[(((size_t)(bb * NHEAD + hh) * DH) + dd) * SEQ + nn] = (_Float16)v;
        }
    }
}

// ---------------------------------------------------------------- attention
// One 64-key tile, software-pipelined: issues K/V loads for tile t+1, does
// QK^T (K arrived one tile ago) + bias-as-C, lane-local defer-max softmax,
// P via LDS, PV (V arrived one tile ago). Named ping-pong register state.
__device__ __forceinline__ void attn_tile(
    int t,
    const _Float16* __restrict__ Kl, const _Float16* __restrict__ Vl0,
    const _Float16* __restrict__ Vl1,
    half8 aq, half8 (&kc)[4], half8 (&kn)[4], half8 (&vc)[4], half8 (&vn)[4],
    const float* __restrict__ biasRow, char* PlW, float* xw,
    float& mrun, float& lsum, f32x4& acc0, f32x4& acc1, int lane, int lg)
{
    const int tn = (t + 1) & (SEQ / 64 - 1);

    // ---- issue next tile's K/V loads (consumed one tile later)
#pragma unroll
    for (int cf = 0; cf < 4; ++cf)
        kn[cf] = *reinterpret_cast<const half8*>(
            Kl + (size_t)(tn * 64 + cf * 16) * DH);
    vn[0] = *reinterpret_cast<const half8*>(Vl0 + tn * 64);
    vn[1] = *reinterpret_cast<const half8*>(Vl1 + tn * 64);
    vn[2] = *reinterpret_cast<const half8*>(Vl0 + tn * 64 + 32);
    vn[3] = *reinterpret_cast<const half8*>(Vl1 + tn * 64 + 32);

    // ---- S^T = K Q^T + bias (bias rides the C operand)
    const int sb = (t & 7) * 64;
    f32x4 vv[4];
    __builtin_amdgcn_s_setprio(1);
#pragma unroll
    for (int cf = 0; cf < 4; ++cf) {
        f32x4 cb = *reinterpret_cast<const f32x4*>(biasRow + sb + cf * 16 + lg * 4);
        vv[cf] = __builtin_amdgcn_mfma_f32_16x16x32_f16(kc[cf], aq, cb, 0, 0, 0);
    }
    __builtin_amdgcn_s_setprio(0);

    // ---- lane-local defer-max online softmax (log2 domain)
    float m0 = fmaxf(fmaxf(vv[0][0], vv[0][1]), vv[0][2]);
    float m1 = fmaxf(fmaxf(vv[0][3], vv[1][0]), vv[1][1]);
    float m2 = fmaxf(fmaxf(vv[1][2], vv[1][3]), vv[2][0]);
    float m3 = fmaxf(fmaxf(vv[2][1], vv[2][2]), vv[2][3]);
    float m4 = fmaxf(fmaxf(vv[3][0], vv[3][1]), vv[3][2]);
    float tmax = fmaxf(fmaxf(fmaxf(m0, m1), fmaxf(m2, m3)),
                       fmaxf(m4, vv[3][3]));

    if (!__all(tmax <= mrun + THR_L2)) {     // rare rescale path
        float tm = tmax;
        tm = fmaxf(tm, __shfl_xor(tm, 16, 64));
        tm = fmaxf(tm, __shfl_xor(tm, 32, 64));
        const float mnew  = fmaxf(mrun, tm);
        const float alpha = fast_exp2(mrun - mnew);
        if (lane < 16) xw[lane] = alpha;
        f32x4 a4 = *reinterpret_cast<const f32x4*>(&xw[lg * 4]);
        lsum *= alpha;
        mrun = mnew;
        acc0 *= a4;
        acc1 *= a4;
    }

    const int lr = lane & 15;
#pragma unroll
    for (int cf = 0; cf < 4; ++cf) {
        float p0 = fast_exp2(vv[cf][0] - mrun);
        float p1 = fast_exp2(vv[cf][1] - mrun);
        float p2 = fast_exp2(vv[cf][2] - mrun);
        float p3 = fast_exp2(vv[cf][3] - mrun);
        lsum += (p0 + p1) + (p2 + p3);
        fp16x2 ha = __builtin_amdgcn_cvt_pkrtz(p0, p1);
        fp16x2 hb = __builtin_amdgcn_cvt_pkrtz(p2, p3);
        unsigned int wlo = __builtin_bit_cast(unsigned int, ha);
        unsigned int whi = __builtin_bit_cast(unsigned int, hb);
        unsigned long long wq =
            (unsigned long long)wlo | ((unsigned long long)whi << 32);
        *reinterpret_cast<unsigned long long*>(
            PlW + lr * 144 + (cf * 16 + lg * 4) * 2) = wq;
    }

    // ---- PV: acc += P(16x64) @ V(64x32); wave-private P
    half8 pa0 = *reinterpret_cast<const half8*>(PlW + lr * 144 + (lg * 8) * 2);
    half8 pa1 = *reinterpret_cast<const half8*>(PlW + lr * 144 + (32 + lg * 8) * 2);
    __builtin_amdgcn_s_setprio(1);
    acc0 = __builtin_amdgcn_mfma_f32_16x16x32_f16(pa0, vc[0], acc0, 0, 0, 0);
    acc1 = __builtin_amdgcn_mfma_f32_16x16x32_f16(pa0, vc[1], acc1, 0, 0, 0);
    acc0 = __builtin_amdgcn_mfma_f32_16x16x32_f16(pa1, vc[2], acc0, 0, 0, 0);
    acc1 = __builtin_amdgcn_mfma_f32_16x16x32_f16(pa1, vc[3], acc1, 0, 0, 0);
    __builtin_amdgcn_s_setprio(0);
}

// grid (SEQ/16, BATCH), 512 threads = 8 waves = 8 heads. i-tile 16 rows.
__global__ __launch_bounds__(512, 4) void attn_kernel(
    const _Float16* __restrict__ Qh, const _Float16* __restrict__ Kh,
    const _Float16* __restrict__ Vt, const float* __restrict__ pos,
    _Float16* __restrict__ AO)
{
    __shared__ __align__(16) float pi4[16][4];
    __shared__ __align__(16) float pj4[512][4];
    __shared__ __align__(16) float biasL[16][516];        // 33 KB
    __shared__ __align__(16) _Float16 Pl[NHEAD][16 * 72]; // 144B row stride
    __shared__ __align__(16) float xposeL[NHEAD][16];

    const int b    = blockIdx.y;
    const int i0   = blockIdx.x * 16;
    const int tid  = threadIdx.x;
    const int w    = tid >> 6;           // head
    const int lane = tid & 63;
    const int lr   = lane & 15, lg = lane >> 4;

    if (tid < 16) {
        const float* p = pos + (size_t)(b * SEQ + i0 + tid) * 3;
        float x = p[0], y = p[1], z = p[2];
        pi4[tid][0] = x; pi4[tid][1] = y; pi4[tid][2] = z;
        pi4[tid][3] = x * x + y * y + z * z;
    }

    const size_t bhh = (size_t)(b * NHEAD + w);
    const _Float16* Qbase = Qh + (bhh * SEQ + i0) * DH;
    const _Float16* Kl  = Kh + bhh * SEQ * DH + (size_t)lr * DH + lg * 8;
    const _Float16* Vl0 = Vt + bhh * DH * SEQ + (size_t)lr * SEQ + lg * 8;
    const _Float16* Vl1 = Vt + bhh * DH * SEQ + (size_t)(16 + lr) * SEQ + lg * 8;

    const half8 aq = *reinterpret_cast<const half8*>(Qbase + (size_t)lr * DH + lg * 8);

    f32x4 acc0 = {}, acc1 = {};
    float mrun = -1e30f, lsum = 0.f;

    char* PlW = (char*)&Pl[w][0];
    float* xw = &xposeL[w][0];
    const float* biasRow = &biasL[lr][0];

    // pipeline prologue: loads for tile 0
    half8 kA[4], kB[4], vA[4], vB[4];
#pragma unroll
    for (int cf = 0; cf < 4; ++cf)
        kA[cf] = *reinterpret_cast<const half8*>(Kl + (size_t)(cf * 16) * DH);
    vA[0] = *reinterpret_cast<const half8*>(Vl0);
    vA[1] = *reinterpret_cast<const half8*>(Vl1);
    vA[2] = *reinterpret_cast<const half8*>(Vl0 + 32);
    vA[3] = *reinterpret_cast<const half8*>(Vl1 + 32);

    for (int ch = 0; ch < SEQ / 512; ++ch) {
        __syncthreads();                       // protect pj4/biasL from prev chunk readers
        {
            const float* p = pos + (size_t)(b * SEQ + ch * 512 + tid) * 3;
            float x = p[0], y = p[1], z = p[2];
            pj4[tid][0] = x; pj4[tid][1] = y; pj4[tid][2] = z;
            pj4[tid][3] = x * x + y * y + z * z;
        }
        __syncthreads();
        {   // bias tile 16 x 512: 16 values per thread, b128 stores
            const int br  = tid & 15;
            const int c0  = (tid >> 4) * 16;
            const float xi = pi4[br][0], yi = pi4[br][1], zi = pi4[br][2], si = pi4[br][3];
#pragma unroll
            for (int k4 = 0; k4 < 4; ++k4) {
                f32x4 o;
#pragma unroll
                for (int k = 0; k < 4; ++k) {
                    const float* pj = &pj4[c0 + k4 * 4 + k][0];
                    float dot = xi * pj[0] + yi * pj[1] + zi * pj[2];
                    float d2  = si + pj[3] - 2.f * dot;
                    o[k] = BIASC * sqrtf(fmaxf(d2, 0.f));
                }
                *reinterpret_cast<f32x4*>(&biasL[br][c0 + k4 * 4]) = o;
            }
        }
        __syncthreads();

        for (int s = 0; s < 4; ++s) {
            const int t = ch * 8 + s * 2;
            attn_tile(t,     Kl, Vl0, Vl1, aq, kA, kB, vA, vB,
                      biasRow, PlW, xw, mrun, lsum, acc0, acc1, lane, lg);
            attn_tile(t + 1, Kl, Vl0, Vl1, aq, kB, kA, vB, vA,
                      biasRow, PlW, xw, mrun, lsum, acc0, acc1, lane, lg);
        }
    }

    // ---- epilogue
    lsum += __shfl_xor(lsum, 16, 64);
    lsum += __shfl_xor(lsum, 32, 64);
    const float inv = 1.f / lsum;                    // lane layout i=lr
    if (lane < 16) xw[lane] = inv;
    f32x4 i4 = *reinterpret_cast<const f32x4*>(&xw[lg * 4]);
#pragma unroll
    for (int t = 0; t < 4; ++t) {
        const size_t row = (size_t)(b * SEQ + i0 + lg * 4 + t) * HID + w * DH;
        AO[row + lr]      = (_Float16)(acc0[t] * i4[t]);
        AO[row + 16 + lr] = (_Float16)(acc1[t] * i4[t]);
    }
}

// ---------------------------------------------------------------- out proj
__global__ __launch_bounds__(256) void out_proj(
    const _Float16* __restrict__ AO, const _Float16* __restrict__ Woh,
    const float* __restrict__ bo, float* __restrict__ out)
{
    const int m0  = blockIdx.x * 64;
    const int n0  = blockIdx.y * 64;
    const int tid = threadIdx.x;
    const int w   = tid >> 6, lane = tid & 63;
    const int lr  = lane & 15, lg = lane >> 4;
    const int wr  = (w >> 1) * 32, wc = (w & 1) * 32;

    f32x4 acc[2][2] = {};
    const int ar = m0 + wr + lr;
    const int br = n0 + wc + lr;
#pragma unroll
    for (int ks = 0; ks < 8; ++ks) {
        const int ko = ks * 32 + lg * 8;
        half8 a0 = *reinterpret_cast<const half8*>(AO + (size_t)ar * HID + ko);
        half8 a1 = *reinterpret_cast<const half8*>(AO + (size_t)(ar + 16) * HID + ko);
        half8 b0 = *reinterpret_cast<const half8*>(Woh + (size_t)br * HID + ko);
        half8 b1 = *reinterpret_cast<const half8*>(Woh + (size_t)(br + 16) * HID + ko);
        acc[0][0] = __builtin_amdgcn_mfma_f32_16x16x32_f16(a0, b0, acc[0][0], 0, 0, 0);
        acc[0][1] = __builtin_amdgcn_mfma_f32_16x16x32_f16(a0, b1, acc[0][1], 0, 0, 0);
        acc[1][0] = __builtin_amdgcn_mfma_f32_16x16x32_f16(a1, b0, acc[1][0], 0, 0, 0);
        acc[1][1] = __builtin_amdgcn_mfma_f32_16x16x32_f16(a1, b1, acc[1][1], 0, 0, 0);
    }
#pragma unroll
    for (int mf = 0; mf < 2; ++mf)
#pragma unroll
    for (int nf = 0; nf < 2; ++nf)
#pragma unroll
    for (int r = 0; r < 4; ++r) {
        const int m = m0 + wr + mf * 16 + lg * 4 + r;
        const int o = n0 + wc + nf * 16 + lr;
        out[(size_t)m * HID + o] = acc[mf][nf][r] + bo[o];
    }
}

// ---------------------------------------------------------------- launch
extern "C" void kernel_launch(void* const* d_in, const int* in_sizes, int n_in,
                              void* d_out, int out_size, void* d_ws, size_t ws_size,
                              hipStream_t stream)
{
    const float* x   = (const float*)d_in[0];
    const float* pos = (const float*)d_in[1];
    const float* Wq  = (const float*)d_in[2];
    const float* bq  = (const float*)d_in[3];
    const float* Wk  = (const float*)d_in[4];
    const float* bk  = (const float*)d_in[5];
    const float* Wv  = (const float*)d_in[6];
    const float* bv  = (const float*)d_in[7];
    const float* Wo  = (const float*)d_in[8];
    const float* bo  = (const float*)d_in[9];
    float* out = (float*)d_out;

    char* ws = (char*)d_ws;
    _Float16* Qh = (_Float16*)(ws);                 // 4 MB
    _Float16* Kh = (_Float16*)(ws + (4  << 20));    // 4 MB
    _Float16* Vt = (_Float16*)(ws + (8  << 20));    // 4 MB
    _Float16* xh = (_Float16*)(ws + (12 << 20));    // 4 MB (reused as AO)
    _Float16* AO = xh;                              // safe: attn runs after qkv_proj
    _Float16* Wh = (_Float16*)(ws + (16 << 20));    // 512 KB

    const int NX = BATCH * SEQ * HID;               // 2,097,152
    const int NW = HID * HID;                       // 65,536
    cvt_f32_f16<<<NX / 1024, 256, 0, stream>>>(x, xh, NX);
    cvt_w4<<<dim3(NW / 1024, 4), 256, 0, stream>>>(Wq, Wk, Wv, Wo, Wh);

    qkv_proj<<<dim3(BATCH * SEQ / 64, HID / 64, 3), 256, 0, stream>>>(
        xh, Wh, bq, bk, bv, Qh, Kh, Vt);

    attn_kernel<<<dim3(SEQ / 16, BATCH), 512, 0, stream>>>(Qh, Kh, Vt, pos, AO);

    out_proj<<<dim3(BATCH * SEQ / 64, HID / 64), 256, 0, stream>>>(
        AO, Wh + 3 * NW, bo, out);
}